// Round 2
// baseline (300.055 us; speedup 1.0000x reference)
//
#include <hip/hip_runtime.h>
#include <hip/hip_bf16.h>
#include <math.h>

typedef __bf16 bf16x8 __attribute__((ext_vector_type(8)));
typedef float f32x4 __attribute__((ext_vector_type(4)));

__device__ __forceinline__ float toF(__hip_bfloat16 v){ return __bfloat162float(v); }
__device__ __forceinline__ float toF(float v){ return v; }
__device__ __forceinline__ __hip_bfloat16 f2bf(float v){ return __float2bfloat16(v); }

// ---------------- weight transpose+convert: in f32[K][N] -> out bf16[N][K] ----------------
__global__ void transpose_f2b(const float* __restrict__ in,
                              __hip_bfloat16* __restrict__ out, int K, int N){
  __shared__ float tile[32][33];
  int tx = threadIdx.x, ty = threadIdx.y;
  int n0 = blockIdx.x*32, k0 = blockIdx.y*32;
#pragma unroll
  for(int i=0;i<4;i++) tile[ty+i*8][tx] = in[(size_t)(k0+ty+i*8)*N + n0+tx];
  __syncthreads();
#pragma unroll
  for(int i=0;i<4;i++) out[(size_t)(n0+ty+i*8)*K + k0+tx] = f2bf(tile[tx][ty+i*8]);
}

// ---------------- LayerNorm over C=768, one row per block; f32 in -> bf16 out ----------------
__global__ __launch_bounds__(256) void ln_kernel(const float* __restrict__ in,
    const float* __restrict__ g, const float* __restrict__ b,
    __hip_bfloat16* __restrict__ out){
  int row = blockIdx.x, t = threadIdx.x;
  const float* rp = in + (size_t)row*768;
  float x0 = rp[t], x1 = rp[t+256], x2 = rp[t+512];
  float s = x0+x1+x2, ss = x0*x0+x1*x1+x2*x2;
#pragma unroll
  for(int o=32;o>0;o>>=1){ s += __shfl_down(s,o); ss += __shfl_down(ss,o); }
  __shared__ float red[10];
  if((t&63)==0){ red[t>>6]=s; red[4+(t>>6)]=ss; }
  __syncthreads();
  if(t==0){
    float S=red[0]+red[1]+red[2]+red[3], SS=red[4]+red[5]+red[6]+red[7];
    float m=S*(1.f/768.f);
    red[8]=m; red[9]=SS*(1.f/768.f)-m*m;
  }
  __syncthreads();
  float m=red[8], r=rsqrtf(red[9]+1e-5f);
  __hip_bfloat16* op = out + (size_t)row*768;
  op[t]     = f2bf((x0-m)*r*g[t]     + b[t]);
  op[t+256] = f2bf((x1-m)*r*g[t+256] + b[t+256]);
  op[t+512] = f2bf((x2-m)*r*g[t+512] + b[t+512]);
}

// ---------------- GEMM: C[M][N] = A[M][K] * B, B given as BT[N][K] (both bf16) ----------------
// EPI: 0=plain bf16  1=KV split (+tem_mask f32 on V)  2=+resid(f32)->f32  3=gelu->bf16  4=+resid(f32)->f32 out
template<int EPI>
__global__ __launch_bounds__(256) void gemm_bt(
    const __hip_bfloat16* __restrict__ A, const __hip_bfloat16* __restrict__ BT,
    const float* __restrict__ bias, int M, int N, int K,
    void* __restrict__ out, const void* __restrict__ aux0, void* __restrict__ out2){
  __shared__ char sA[128*128];   // 128 rows x 64 bf16 (128B), XOR-swizzled
  __shared__ char sB[128*128];
  const int tid = threadIdx.x;
  const int l = tid & 63, w = tid >> 6;
  const int wm = w >> 1, wn = w & 1;
  const int lg = l >> 4, li = l & 15;
  const int bm = blockIdx.x * 128;
  const int bn = blockIdx.y * 128;

  f32x4 acc[4][4] = {};
  const int nk = K >> 6;
  for(int kt=0; kt<nk; ++kt){
    const int k0 = kt*64;
#pragma unroll
    for(int it=0; it<4; ++it){
      int item = it*256 + tid;
      int row = item >> 3, slot = item & 7;
      int off = row*128 + ((slot*16) ^ ((row&7)<<4));
      uint4 va = *(const uint4*)(A  + (size_t)(bm+row)*K + k0 + slot*8);
      uint4 vb = *(const uint4*)(BT + (size_t)(bn+row)*K + k0 + slot*8);
      *(uint4*)(sA + off) = va;
      *(uint4*)(sB + off) = vb;
    }
    __syncthreads();
#pragma unroll
    for(int kk=0; kk<2; ++kk){
      const int kb = kk*64 + lg*16;
      bf16x8 af[4], bfr[4];
#pragma unroll
      for(int m=0;m<4;m++){
        int row = wm*64 + m*16 + li;
        af[m] = *(const bf16x8*)(sA + row*128 + (kb ^ ((row&7)<<4)));
      }
#pragma unroll
      for(int n=0;n<4;n++){
        int row = wn*64 + n*16 + li;
        bfr[n] = *(const bf16x8*)(sB + row*128 + (kb ^ ((row&7)<<4)));
      }
#pragma unroll
      for(int m=0;m<4;m++)
#pragma unroll
        for(int n=0;n<4;n++)
          acc[m][n] = __builtin_amdgcn_mfma_f32_16x16x32_bf16(af[m], bfr[n], acc[m][n], 0,0,0);
    }
    __syncthreads();
  }
  // epilogue
#pragma unroll
  for(int m=0;m<4;m++){
#pragma unroll
    for(int n=0;n<4;n++){
#pragma unroll
      for(int r=0;r<4;r++){
        int row = bm + wm*64 + m*16 + lg*4 + r;
        int col = bn + wn*64 + n*16 + li;
        float v = acc[m][n][r] + bias[col];
        if constexpr(EPI==0){
          ((__hip_bfloat16*)out)[(size_t)row*N + col] = f2bf(v);
        } else if constexpr(EPI==1){
          if(col < 768){
            ((__hip_bfloat16*)out)[(size_t)row*768 + col] = f2bf(v);
          } else {
            int c = col - 768;
            int bb = row / 1344, ii = row % 1344;
            if(ii < 320) v += ((const float*)aux0)[((size_t)bb*320 + ii)*768 + c];
            ((__hip_bfloat16*)out2)[(size_t)row*768 + c] = f2bf(v);
          }
        } else if constexpr(EPI==2){
          v += ((const float*)aux0)[(size_t)row*N + col];
          ((float*)out)[(size_t)row*N + col] = v;
        } else if constexpr(EPI==3){
          float gl = 0.5f * v * (1.0f + erff(v * 0.70710678118654752f));
          ((__hip_bfloat16*)out)[(size_t)row*N + col] = f2bf(gl);
        } else {
          v += ((const float*)aux0)[(size_t)row*N + col];
          ((float*)out)[(size_t)row*N + col] = v;
        }
      }
    }
  }
}

// ---------------- fused attention: one block per (b, h, 64-row Q tile) ----------------
__global__ __launch_bounds__(256) void attn_kernel(
    const __hip_bfloat16* __restrict__ qh,  // (B*LQ, 768)
    const __hip_bfloat16* __restrict__ kb,  // (B*LKV, 768)
    const __hip_bfloat16* __restrict__ vb,  // (B*LKV, 768)
    const float* __restrict__ pos,          // (H, LQ, LKV) f32
    __hip_bfloat16* __restrict__ xo){       // (B*LQ, 768)
  __shared__ char sK[64*128];      // K-tile row-major [kv][d], swizzled
  __shared__ char sV[64*128];      // V-tile transposed [d][kv], swizzled
  __shared__ char sP[4*16*128];    // per-wave P tile [16][64], swizzled
  const int blk = blockIdx.x;
  const int qt = blk & 15, h = (blk >> 4) % 12, b = blk / 192;
  const int q0 = qt * 64;
  const int tid = threadIdx.x;
  const int l = tid & 63, w = tid >> 6;
  const int lg = l >> 4, li = l & 15;

  bf16x8 aq[2];
  {
    const char* qp = (const char*)(qh + ((size_t)(b*1024 + q0 + w*16 + li))*768 + h*64);
    aq[0] = *(const bf16x8*)(qp + lg*16);
    aq[1] = *(const bf16x8*)(qp + 64 + lg*16);
  }

  f32x4 accO[4] = {};
  float mrun[4], lrun[4];
#pragma unroll
  for(int r=0;r<4;r++){ mrun[r] = -1e30f; lrun[r] = 0.f; }

  for(int t=0; t<21; ++t){
    const int kv0 = t*64;
#pragma unroll
    for(int it=0; it<2; ++it){
      int item = it*256 + tid;
      int row = item >> 3, slot = item & 7;
      uint4 vk = *(const uint4*)(kb + ((size_t)(b*1344 + kv0 + row))*768 + h*64 + slot*8);
      *(uint4*)(sK + row*128 + ((slot*16) ^ ((row&7)<<4))) = vk;
      uint4 vv = *(const uint4*)(vb + ((size_t)(b*1344 + kv0 + row))*768 + h*64 + slot*8);
      const __hip_bfloat16* ue = (const __hip_bfloat16*)&vv;
#pragma unroll
      for(int i=0;i<8;i++){
        int d = slot*8 + i;
        *(__hip_bfloat16*)(sV + d*128 + ((row*2) ^ ((d&7)<<4))) = ue[i];
      }
    }
    __syncthreads();

    // S = Q K^T
    f32x4 accS[4] = {};
#pragma unroll
    for(int kk=0; kk<2; ++kk){
      const int kbyte = kk*64 + lg*16;
#pragma unroll
      for(int n=0;n<4;n++){
        int row = n*16 + li;
        bf16x8 bkf = *(const bf16x8*)(sK + row*128 + (kbyte ^ ((row&7)<<4)));
        accS[n] = __builtin_amdgcn_mfma_f32_16x16x32_bf16(aq[kk], bkf, accS[n], 0,0,0);
      }
    }
    // scale + pos + online softmax
    float p[4][4], mt[4];
#pragma unroll
    for(int r=0;r<4;r++) mt[r] = -1e30f;
#pragma unroll
    for(int n=0;n<4;n++){
      const float* pp = pos + ((size_t)h*1024 + q0 + w*16 + lg*4)*1344 + kv0 + n*16 + li;
#pragma unroll
      for(int r=0;r<4;r++){
        float s = accS[n][r]*0.125f + pp[(size_t)r*1344];
        p[n][r] = s;
        mt[r] = fmaxf(mt[r], s);
      }
    }
    char* sPw = sP + w*2048;
#pragma unroll
    for(int r=0;r<4;r++){
#pragma unroll
      for(int o=1;o<16;o<<=1) mt[r] = fmaxf(mt[r], __shfl_xor(mt[r], o));
      float mnew = fmaxf(mrun[r], mt[r]);
      float sf = __expf(mrun[r]-mnew);
      mrun[r] = mnew;
      lrun[r] *= sf;
#pragma unroll
      for(int n=0;n<4;n++) accO[n][r] *= sf;
      float rs = 0.f;
#pragma unroll
      for(int n=0;n<4;n++){ p[n][r] = __expf(p[n][r]-mnew); rs += p[n][r]; }
#pragma unroll
      for(int o=1;o<16;o<<=1) rs += __shfl_xor(rs, o);
      lrun[r] += rs;
    }
    // write P tile (per wave)
#pragma unroll
    for(int n=0;n<4;n++){
#pragma unroll
      for(int r=0;r<4;r++){
        int qi = lg*4 + r, kj = n*16 + li;
        *(__hip_bfloat16*)(sPw + qi*128 + ((kj*2) ^ ((qi&7)<<4))) = f2bf(p[n][r]);
      }
    }
    __syncthreads();  // order P/sV writes vs reads across the block
    // O += P V
#pragma unroll
    for(int kk=0; kk<2; ++kk){
      const int kbyte = kk*64 + lg*16;
      bf16x8 pa = *(const bf16x8*)(sPw + li*128 + (kbyte ^ ((li&7)<<4)));
#pragma unroll
      for(int n=0;n<4;n++){
        int d = n*16 + li;
        bf16x8 bvf = *(const bf16x8*)(sV + d*128 + (kbyte ^ ((d&7)<<4)));
        accO[n] = __builtin_amdgcn_mfma_f32_16x16x32_bf16(pa, bvf, accO[n], 0,0,0);
      }
    }
    __syncthreads();
  }
#pragma unroll
  for(int n=0;n<4;n++){
#pragma unroll
    for(int r=0;r<4;r++){
      int row = b*1024 + q0 + w*16 + lg*4 + r;
      int col = h*64 + n*16 + li;
      xo[(size_t)row*768 + col] = f2bf(accO[n][r] / lrun[r]);
    }
  }
}

extern "C" void kernel_launch(void* const* d_in, const int* in_sizes, int n_in,
                              void* d_out, int out_size, void* d_ws, size_t ws_size,
                              hipStream_t stream){
  const float* tem   = (const float*)d_in[0];
  const float* qin   = (const float*)d_in[1];
  const float* kvin  = (const float*)d_in[2];
  const float* pos   = (const float*)d_in[3];
  const float* ln1qg = (const float*)d_in[4];
  const float* ln1qb = (const float*)d_in[5];
  const float* ln1kg = (const float*)d_in[6];
  const float* ln1kb = (const float*)d_in[7];
  const float* Wq    = (const float*)d_in[8];
  const float* bq    = (const float*)d_in[9];
  const float* Wkv   = (const float*)d_in[10];
  const float* bkv   = (const float*)d_in[11];
  const float* Wp    = (const float*)d_in[12];
  const float* bp    = (const float*)d_in[13];
  const float* ln2g  = (const float*)d_in[14];
  const float* ln2b  = (const float*)d_in[15];
  const float* W1    = (const float*)d_in[16];
  const float* b1    = (const float*)d_in[17];
  const float* W2    = (const float*)d_in[18];
  const float* b2    = (const float*)d_in[19];

  char* ws = (char*)d_ws; size_t off = 0;
  auto alloc = [&](size_t n){ char* p = ws + off; off = (off + n + 255) & ~(size_t)255; return p; };
  __hip_bfloat16* WqT  = (__hip_bfloat16*)alloc((size_t)768*768*2);
  __hip_bfloat16* WkvT = (__hip_bfloat16*)alloc((size_t)1536*768*2);
  __hip_bfloat16* WpT  = (__hip_bfloat16*)alloc((size_t)768*768*2);
  __hip_bfloat16* W1T  = (__hip_bfloat16*)alloc((size_t)3072*768*2);
  __hip_bfloat16* W2T  = (__hip_bfloat16*)alloc((size_t)768*3072*2);
  __hip_bfloat16* qn   = (__hip_bfloat16*)alloc((size_t)4096*768*2);
  char* poolBase = alloc((size_t)5376*768*2*3 + (size_t)4096*768*2); // kvn,kbuf,vbuf,qhb pool
  __hip_bfloat16* kvn  = (__hip_bfloat16*)poolBase;
  __hip_bfloat16* kbuf = kvn  + (size_t)5376*768;
  __hip_bfloat16* vbuf = kbuf + (size_t)5376*768;
  __hip_bfloat16* qhb  = vbuf + (size_t)5376*768;
  __hip_bfloat16* xat  = (__hip_bfloat16*)alloc((size_t)4096*768*2);
  float*          x1f  = (float*)alloc((size_t)4096*768*4);
  // aliases for late-phase buffers (earlier ones provably dead):
  __hip_bfloat16* hln  = qn;                      // qn dead after gemm<0>
  __hip_bfloat16* h1   = kvn;                     // kvn/kbuf/vbuf/qhb dead after attn; 25.2MB fits their 39.3MB pool

  dim3 tb(32,8);
  transpose_f2b<<<dim3(768/32, 768/32),  tb, 0, stream>>>(Wq,  WqT,  768, 768);
  transpose_f2b<<<dim3(1536/32, 768/32), tb, 0, stream>>>(Wkv, WkvT, 768, 1536);
  transpose_f2b<<<dim3(768/32, 768/32),  tb, 0, stream>>>(Wp,  WpT,  768, 768);
  transpose_f2b<<<dim3(3072/32, 768/32), tb, 0, stream>>>(W1,  W1T,  768, 3072);
  transpose_f2b<<<dim3(768/32, 3072/32), tb, 0, stream>>>(W2,  W2T,  3072, 768);

  ln_kernel<<<4096, 256, 0, stream>>>(qin,  ln1qg, ln1qb, qn);
  ln_kernel<<<5376, 256, 0, stream>>>(kvin, ln1kg, ln1kb, kvn);

  gemm_bt<0><<<dim3(32, 6),  256, 0, stream>>>(qn,  WqT,  bq,  4096, 768,  768,  qhb, nullptr, nullptr);
  gemm_bt<1><<<dim3(42, 12), 256, 0, stream>>>(kvn, WkvT, bkv, 5376, 1536, 768,  kbuf, tem, vbuf);

  attn_kernel<<<768, 256, 0, stream>>>(qhb, kbuf, vbuf, pos, xat);

  gemm_bt<2><<<dim3(32, 6),  256, 0, stream>>>(xat, WpT,  bp,  4096, 768,  768,  x1f, qin, nullptr);
  ln_kernel<<<4096, 256, 0, stream>>>(x1f, ln2g, ln2b, hln);
  gemm_bt<3><<<dim3(32, 24), 256, 0, stream>>>(hln, W1T,  b1,  4096, 3072, 768,  h1, nullptr, nullptr);
  gemm_bt<4><<<dim3(32, 6),  256, 0, stream>>>(h1,  W2T,  b2,  4096, 768,  3072, (float*)d_out, x1f, nullptr);
}